// Round 18
// baseline (19.650 us; speedup 1.0000x reference)
//
#include <hip/hip_runtime.h>

#define C_IN  32
#define O_OUT 48
#define H_IN  96
#define W_IN  96
#define H_OUT 192
#define W_OUT 192
#define HW_IN (H_IN * W_IN)
#define NCBLK 192               // compute blocks: 2 b x 96 rows
#define NFBLK 16                // frame blocks: 2 b x 2 side x 4 o-groups
#define LPAD  40                // xs row stride (elems)
#define XS_BYTES (3 * 100 * LPAD * 2)   // 24000
#define WOS   516               // weight LDS stride per o (dwords)
#define CSTR  196               // cbuf stride per o-row (dwords)
#define CPL   (O_OUT * CSTR)    // cbuf plane stride (dwords) = 9408

typedef __attribute__((ext_vector_type(8))) short bf16x8;
typedef __attribute__((ext_vector_type(4))) float f32x4;

__device__ __forceinline__ unsigned short f2bf(float f) {
    union { float f; unsigned u; } v; v.f = f;
    unsigned u = v.u + 0x7FFFu + ((v.u >> 16) & 1u);
    return (unsigned short)(u >> 16);
}

// ---------------------------------------------------------------------------
// Single kernel, two block roles, 768-thread blocks, 208 blocks
// (one generation across 256 CUs).
//
// Compute blocks [0,192): (b,row).
//   A1: transpose 3x(96+2halo)x32 x-slab to LDS bf16 -- 288 threads, float4
//       loads (4 cols x 8 ch) -> 2.3K lane-addresses (was 4.6K float2).
//   A2: stage raw weights (98KB) to LDS, coalesced (6.1K addresses).
//   barrier1 -> A-build from LDS weights (parity norm + row-edge folded)
//   barrier2 -> MFMA; results to LDS cbuf[2][48][CSTR] via ds_write_b64
//   barrier3 -> readout: 6 float4 global stores/thread, linear per (pe,oo)
//       row -> 4.6K lane-addresses (was 9.2K float2). wo in {0,191} skipped
//       (frame blocks own them). cbuf ALIASES the weight buffer (dead after
//       A-build).
//
// Frame blocks [192,208): border columns wo in {0,191}, full ho 0..191,
// from an LDS-staged x column.
//
// Tap map (ts=a*2+d), pe=0 (even ho=2s): a0->i=1 (x row s), a1->i=3 (s-1)
//                     pe=1 (odd  ho)   : a0->i=0 (s+1),     a1->i=2 (s)
// po=0 (even wo=2t): d0->j=1 (col t), d1->j=3 (t-1)
// po=1 (odd  wo)   : d0->j=0 (t+1),  d1->j=2 (t)
// ---------------------------------------------------------------------------
__global__ __launch_bounds__(768) void nct_all(
    const float* __restrict__ x,       // [2,32,96,96]
    const float* __restrict__ weight,  // [48,32,4,4]
    const float* __restrict__ bias,    // [48]
    float* __restrict__ out)           // [2,48,192,192]
{
    // xs 24000B | wl f32[48][516] = 99072B (aliased by cbuf f32[2][48][196] = 75264B)
    __shared__ __align__(16) unsigned char smem[XS_BYTES + O_OUT * WOS * 4];
    const int blk = blockIdx.x;
    const int tid = threadIdx.x;

    if (blk < NCBLK) {
        auto xs = (unsigned short (*)[100][LPAD])smem;
        float* wl   = (float*)(smem + XS_BYTES);
        float* cbuf = (float*)(smem + XS_BYTES);

        const int b   = blk / 96;
        const int row = blk % 96;

        const int r3[3] = { (row > 0) ? row - 1 : 0, row, (row < H_IN - 1) ? row + 1 : H_IN - 1 };

        // ---- A1: transpose 3 rows x 96 cols x 32 ch (float4, 288 threads) ----
        if (tid < 288) {
            const int r   = tid / 96;
            const int rem = tid - r * 96;
            const int q   = rem >> 2;       // col quad 0..23
            const int cg  = rem & 3;        // channel group of 8
            const int col0 = q * 4;
            const float* src = x + (size_t)(b * C_IN + cg * 8) * HW_IN + r3[r] * W_IN + col0;
            float4 v[8];
            #pragma unroll
            for (int k = 0; k < 8; ++k) v[k] = *(const float4*)(src + (size_t)k * HW_IN);
            #pragma unroll
            for (int j = 0; j < 4; ++j) {
                const float vj[8] = { j==0?v[0].x:j==1?v[0].y:j==2?v[0].z:v[0].w,
                                      j==0?v[1].x:j==1?v[1].y:j==2?v[1].z:v[1].w,
                                      j==0?v[2].x:j==1?v[2].y:j==2?v[2].z:v[2].w,
                                      j==0?v[3].x:j==1?v[3].y:j==2?v[3].z:v[3].w,
                                      j==0?v[4].x:j==1?v[4].y:j==2?v[4].z:v[4].w,
                                      j==0?v[5].x:j==1?v[5].y:j==2?v[5].z:v[5].w,
                                      j==0?v[6].x:j==1?v[6].y:j==2?v[6].z:v[6].w,
                                      j==0?v[7].x:j==1?v[7].y:j==2?v[7].z:v[7].w };
                unsigned pk[4];
                #pragma unroll
                for (int m = 0; m < 4; ++m)
                    pk[m] = (unsigned)f2bf(vj[2 * m]) | ((unsigned)f2bf(vj[2 * m + 1]) << 16);
                *(uint4*)(&xs[r][col0 + j + 1][cg * 8]) = make_uint4(pk[0], pk[1], pk[2], pk[3]);
            }
        } else if (tid < 312) {
            // halo pixels: pix 0 (col -1 -> clamp 0), pix 97 (col 96 -> clamp 95)
            const int h    = tid - 288;      // 0..23 = r(3) x side(2) x cg(4)
            const int r    = h >> 3;
            const int hs   = (h >> 2) & 1;
            const int cg   = h & 3;
            const int colx = hs ? 95 : 0;
            const int pix  = hs ? 97 : 0;
            const float* src = x + (size_t)(b * C_IN + cg * 8) * HW_IN + r3[r] * W_IN + colx;
            unsigned pk[4];
            #pragma unroll
            for (int k = 0; k < 4; ++k) {
                const float f0 = src[(size_t)(2 * k)     * HW_IN];
                const float f1 = src[(size_t)(2 * k + 1) * HW_IN];
                pk[k] = (unsigned)f2bf(f0) | ((unsigned)f2bf(f1) << 16);
            }
            *(uint4*)(&xs[r][pix][cg * 8]) = make_uint4(pk[0], pk[1], pk[2], pk[3]);
        }

        // ---- A2: stage raw weights (98KB) into LDS, fully coalesced ----
        {
            const float4* wsrc = (const float4*)weight;   // 6144 float4s
            #pragma unroll
            for (int k = 0; k < 8; ++k) {
                const int f = tid + k * 768;              // 0..6143
                const int o = f >> 7;
                const int m = f & 127;
                const float4 v = wsrc[f];
                *(float4*)(wl + o * WOS + m * 4) = v;
            }
        }

        const int lane = tid & 63;
        const int wid  = tid >> 6;     // 0..11
        const int half = wid / 6;
        const int sub  = wid % 6;
        const int pe = sub & 1, mt = sub >> 1;
        const int g = lane >> 4, n16 = lane & 15;
        const int c0 = half * 48;

        const float4 bv4 = *(const float4*)(bias + mt * 16 + 4 * g);

        __syncthreads();

        // ---- A-build from LDS weights ----
        const bool etop = (pe == 0 && row == 0);
        const bool ebot = (pe == 1 && row == H_IN - 1);
        const float m0 = ebot ? 0.f : 1.f;
        const float m1 = etop ? 0.f : 1.f;

        const int o = mt * 16 + n16;
        const float* wb0 = wl + o * WOS + g * 128 + (pe ? 0 : 4);
        const float* wb1 = wl + o * WOS + g * 128 + (pe ? 8 : 12);

        bf16x8 A[2][4];
        #pragma unroll
        for (int cc = 0; cc < 8; ++cc) {
            const float4 wa0 = *(const float4*)(wb0 + cc * 16);
            const float4 wa1 = *(const float4*)(wb1 + cc * 16);

            const float r0 = 1.f / (m0 * (wa0.y + wa0.w) + m1 * (wa1.y + wa1.w)); // po=0
            const float r1 = 1.f / (m0 * (wa0.x + wa0.z) + m1 * (wa1.x + wa1.z)); // po=1

            A[0][0][cc] = (short)f2bf(m0 * wa0.y * r0);
            A[0][1][cc] = (short)f2bf(m0 * wa0.w * r0);
            A[0][2][cc] = (short)f2bf(m1 * wa1.y * r0);
            A[0][3][cc] = (short)f2bf(m1 * wa1.w * r0);
            A[1][0][cc] = (short)f2bf(m0 * wa0.x * r1);
            A[1][1][cc] = (short)f2bf(m0 * wa0.z * r1);
            A[1][2][cc] = (short)f2bf(m1 * wa1.x * r1);
            A[1][3][cc] = (short)f2bf(m1 * wa1.z * r1);
        }

        __syncthreads();   // wl dead; cbuf live from here

        const int lr0 = pe ? 2 : 1;
        const int lr1 = pe ? 1 : 0;

        #pragma unroll
        for (int nt = 0; nt < 3; ++nt) {
            const int col = c0 + nt * 16 + n16;
            const int lp  = col + 1;

            const bf16x8 B00 = *(const bf16x8*)(&xs[lr0][lp][g * 8]);
            const bf16x8 B0m = *(const bf16x8*)(&xs[lr0][lp - 1][g * 8]);
            const bf16x8 B0p = *(const bf16x8*)(&xs[lr0][lp + 1][g * 8]);
            const bf16x8 B10 = *(const bf16x8*)(&xs[lr1][lp][g * 8]);
            const bf16x8 B1m = *(const bf16x8*)(&xs[lr1][lp - 1][g * 8]);
            const bf16x8 B1p = *(const bf16x8*)(&xs[lr1][lp + 1][g * 8]);

            f32x4 a0 = {0.f, 0.f, 0.f, 0.f}, a1 = {0.f, 0.f, 0.f, 0.f};
            a0 = __builtin_amdgcn_mfma_f32_16x16x32_bf16(A[0][0], B00, a0, 0, 0, 0);
            a0 = __builtin_amdgcn_mfma_f32_16x16x32_bf16(A[0][1], B0m, a0, 0, 0, 0);
            a0 = __builtin_amdgcn_mfma_f32_16x16x32_bf16(A[0][2], B10, a0, 0, 0, 0);
            a0 = __builtin_amdgcn_mfma_f32_16x16x32_bf16(A[0][3], B1m, a0, 0, 0, 0);
            a1 = __builtin_amdgcn_mfma_f32_16x16x32_bf16(A[1][0], B0p, a1, 0, 0, 0);
            a1 = __builtin_amdgcn_mfma_f32_16x16x32_bf16(A[1][1], B00, a1, 0, 0, 0);
            a1 = __builtin_amdgcn_mfma_f32_16x16x32_bf16(A[1][2], B1p, a1, 0, 0, 0);
            a1 = __builtin_amdgcn_mfma_f32_16x16x32_bf16(A[1][3], B10, a1, 0, 0, 0);

            #pragma unroll
            for (int r = 0; r < 4; ++r) {
                const int oo = mt * 16 + 4 * g + r;
                float* cp = cbuf + pe * CPL + oo * CSTR + 2 * col;
                cp[0] = a0[r] + bv4[r];
                cp[1] = a1[r] + bv4[r];
            }
        }

        __syncthreads();

        // ---- readout: 6 float4 linear stores per thread; skip wo 0 & 191 ----
        const int ho0 = 2 * row;
        #pragma unroll
        for (int k = 0; k < 6; ++k) {
            const int j   = tid + k * 768;        // 0..4607
            const int pej = j / 2304;
            const int rem = j - pej * 2304;
            const int oo  = rem / 48;
            const int wv  = rem - oo * 48;
            const int wo0 = wv * 4;
            const float4 v = *(const float4*)(cbuf + pej * CPL + oo * CSTR + wo0);
            float* p = out + ((size_t)(b * O_OUT + oo) * H_OUT + ho0 + pej) * W_OUT + wo0;
            if (wv == 0) {
                p[1] = v.y;
                *(float2*)(p + 2) = make_float2(v.z, v.w);
            } else if (wv == 47) {
                *(float2*)(p) = make_float2(v.x, v.y);
                p[2] = v.z;
            } else {
                *(float4*)p = v;
            }
        }
    } else {
        // ---- frame: border columns wo in {0,191}, ho 0..191 (corners incl.) ----
        float* xcol = (float*)smem;              // [32][96]

        const int fb   = blk - NCBLK;            // 0..15
        const int b    = fb >> 3;
        const int side = (fb >> 2) & 1;
        const int og   = fb & 3;
        const int colx = side ? 95 : 0;

        for (int idx = tid; idx < C_IN * H_IN; idx += 768) {
            const int c = idx / H_IN;
            const int r = idx - c * H_IN;
            xcol[c * H_IN + r] = x[(size_t)(b * C_IN + c) * HW_IN + r * W_IN + colx];
        }
        __syncthreads();

        if (tid < 384) {
            const int o_loc  = tid >> 5;
            const int ho_loc = tid & 31;
            const int o      = og * 12 + o_loc;
            const int wo     = side ? 191 : 0;
            const int pe     = ho_loc & 1;
            const int jstar  = side ? 2 : 1;

            int   rA[6], rB[6];
            float mBf[6];
            #pragma unroll
            for (int k = 0; k < 6; ++k) {
                const int ho = ho_loc + 32 * k;
                const int s  = ho >> 1;
                rA[k] = s;
                if (pe) { const bool m = (s + 1 < H_IN); rB[k] = m ? s + 1 : H_IN - 1; mBf[k] = m ? 1.f : 0.f; }
                else    { const bool m = (s > 0);        rB[k] = m ? s - 1 : 0;        mBf[k] = m ? 1.f : 0.f; }
            }

            const int iA = pe ? 8 : 4;
            const int iB = pe ? 0 : 12;

            float acc[6] = {0.f, 0.f, 0.f, 0.f, 0.f, 0.f};
            const float* wb = weight + (size_t)o * (C_IN * 16);

            for (int c = 0; c < C_IN; ++c) {
                const float wA = wb[c * 16 + iA + jstar];
                const float wB = wb[c * 16 + iB + jstar];
                const float rn_int  = __builtin_amdgcn_rcpf(wA + wB);
                const float rn_edge = __builtin_amdgcn_rcpf(wA);
                const float* xc = xcol + c * H_IN;
                #pragma unroll
                for (int k = 0; k < 6; ++k) {
                    const float xA = xc[rA[k]];
                    const float xB = xc[rB[k]];
                    const float rn = (mBf[k] != 0.f) ? rn_int : rn_edge;
                    acc[k] += (wA * xA + mBf[k] * (wB * xB)) * rn;
                }
            }

            const float bv = bias[o];
            #pragma unroll
            for (int k = 0; k < 6; ++k) {
                const int ho = ho_loc + 32 * k;
                out[((size_t)(b * O_OUT + o) * H_OUT + ho) * W_OUT + wo] = acc[k] + bv;
            }
        }
    }
}

extern "C" void kernel_launch(void* const* d_in, const int* in_sizes, int n_in,
                              void* d_out, int out_size, void* d_ws, size_t ws_size,
                              hipStream_t stream) {
    const float* x    = (const float*)d_in[0];
    const float* w    = (const float*)d_in[1];
    const float* bias = (const float*)d_in[2];
    float* out = (float*)d_out;

    dim3 b768(768, 1, 1);
    dim3 gm(NCBLK + NFBLK, 1, 1);                  // 208 blocks, single launch
    hipLaunchKernelGGL(nct_all, gm, b768, 0, stream, x, w, bias, out);
}

// Round 19
// 18.957 us; speedup vs baseline: 1.0365x; 1.0365x over previous
//
#include <hip/hip_runtime.h>

#define C_IN  32
#define O_OUT 48
#define H_IN  96
#define W_IN  96
#define H_OUT 192
#define W_OUT 192
#define HW_IN (H_IN * W_IN)
#define NCBLK 192               // compute blocks: 2 b x 96 rows
#define NFBLK 16                // frame blocks: 2 b x 2 side x 4 o-groups
#define LPAD  40                // xs row stride (elems)
#define XS_BYTES (3 * 100 * LPAD * 2)   // 24000
#define WOS   516               // weight LDS stride per o (dwords)

typedef __attribute__((ext_vector_type(8))) short bf16x8;
typedef __attribute__((ext_vector_type(4))) float f32x4;

__device__ __forceinline__ unsigned short f2bf(float f) {
    union { float f; unsigned u; } v; v.f = f;
    unsigned u = v.u + 0x7FFFu + ((v.u >> 16) & 1u);
    return (unsigned short)(u >> 16);
}

// ---------------------------------------------------------------------------
// R16 structure (best measured: 19.10us) + s_setprio around the MFMA cluster.
//
// Compute blocks [0,192): (b,row).
//   A1: transpose 3x(96+2halo)x32 x-slab to LDS bf16 (float2 pair loads).
//   A2: stage raw weights (98KB) to LDS, fully coalesced.
//   barrier -> per-wave A-fragment build from LDS weights (b128 gathers;
//   parity-class reciprocal norm + row-edge class folded) -> MFMA -> direct
//   float2 global stores. wo in {0,191} excluded by store predicates.
//
// Frame blocks [192,208): border columns wo in {0,191}, full ho 0..191,
// from an LDS-staged x column.
//
// Tap map (ts=a*2+d), pe=0 (even ho=2s): a0->i=1 (x row s), a1->i=3 (s-1)
//                     pe=1 (odd  ho)   : a0->i=0 (s+1),     a1->i=2 (s)
// po=0 (even wo=2t): d0->j=1 (col t), d1->j=3 (t-1)
// po=1 (odd  wo)   : d0->j=0 (t+1),  d1->j=2 (t)
// ---------------------------------------------------------------------------
__global__ __launch_bounds__(768) void nct_all(
    const float* __restrict__ x,       // [2,32,96,96]
    const float* __restrict__ weight,  // [48,32,4,4]
    const float* __restrict__ bias,    // [48]
    float* __restrict__ out)           // [2,48,192,192]
{
    __shared__ __align__(16) unsigned char smem[XS_BYTES + O_OUT * WOS * 4];
    const int blk = blockIdx.x;
    const int tid = threadIdx.x;

    if (blk < NCBLK) {
        auto xs = (unsigned short (*)[100][LPAD])smem;
        float* wl = (float*)(smem + XS_BYTES);

        const int b   = blk / 96;
        const int row = blk % 96;

        const int r3[3] = { (row > 0) ? row - 1 : 0, row, (row < H_IN - 1) ? row + 1 : H_IN - 1 };

        // ---- A1: transpose 3 rows x 98 pixel-cols x 32 c into LDS ----
        if (tid < 576) {
            const int r   = tid / 192;
            const int rem = tid - r * 192;
            const int pp  = rem >> 2;       // 0..47
            const int cg  = rem & 3;
            const int col = 2 * pp;
            const float* src = x + (size_t)(b * C_IN + cg * 8) * HW_IN + r3[r] * W_IN + col;
            float v0[8], v1[8];
            #pragma unroll
            for (int k = 0; k < 8; ++k) {
                const float2 v = *(const float2*)(src + (size_t)k * HW_IN);
                v0[k] = v.x; v1[k] = v.y;
            }
            unsigned p0[4], p1[4];
            #pragma unroll
            for (int k = 0; k < 4; ++k) {
                p0[k] = (unsigned)f2bf(v0[2 * k]) | ((unsigned)f2bf(v0[2 * k + 1]) << 16);
                p1[k] = (unsigned)f2bf(v1[2 * k]) | ((unsigned)f2bf(v1[2 * k + 1]) << 16);
            }
            *(uint4*)(&xs[r][col + 1][cg * 8]) = make_uint4(p0[0], p0[1], p0[2], p0[3]);
            *(uint4*)(&xs[r][col + 2][cg * 8]) = make_uint4(p1[0], p1[1], p1[2], p1[3]);
        } else if (tid < 600) {
            // halo pixels: pix 0 (col -1 -> clamp 0), pix 97 (col 96 -> clamp 95)
            const int h    = tid - 576;      // 0..23 = r(3) x side(2) x cg(4)
            const int r    = h >> 3;
            const int hs   = (h >> 2) & 1;
            const int cg   = h & 3;
            const int colx = hs ? 95 : 0;
            const int pix  = hs ? 97 : 0;
            const float* src = x + (size_t)(b * C_IN + cg * 8) * HW_IN + r3[r] * W_IN + colx;
            unsigned pk[4];
            #pragma unroll
            for (int k = 0; k < 4; ++k) {
                const float f0 = src[(size_t)(2 * k)     * HW_IN];
                const float f1 = src[(size_t)(2 * k + 1) * HW_IN];
                pk[k] = (unsigned)f2bf(f0) | ((unsigned)f2bf(f1) << 16);
            }
            *(uint4*)(&xs[r][pix][cg * 8]) = make_uint4(pk[0], pk[1], pk[2], pk[3]);
        }

        // ---- A2: stage raw weights (98KB) into LDS, fully coalesced ----
        {
            const float4* wsrc = (const float4*)weight;   // 6144 float4s
            #pragma unroll
            for (int k = 0; k < 8; ++k) {
                const int f = tid + k * 768;              // 0..6143
                const int o = f >> 7;
                const int m = f & 127;
                const float4 v = wsrc[f];
                *(float4*)(wl + o * WOS + m * 4) = v;
            }
        }

        const int lane = tid & 63;
        const int wid  = tid >> 6;     // 0..11
        const int half = wid / 6;
        const int sub  = wid % 6;
        const int pe = sub & 1, mt = sub >> 1;
        const int g = lane >> 4, n16 = lane & 15;
        const int c0 = half * 48;

        const float4 bv4 = *(const float4*)(bias + mt * 16 + 4 * g);

        __syncthreads();

        // ---- A-fragment build from LDS weights ----
        const bool etop = (pe == 0 && row == 0);
        const bool ebot = (pe == 1 && row == H_IN - 1);
        const float m0 = ebot ? 0.f : 1.f;
        const float m1 = etop ? 0.f : 1.f;

        const int o = mt * 16 + n16;
        const float* wb0 = wl + o * WOS + g * 128 + (pe ? 0 : 4);
        const float* wb1 = wl + o * WOS + g * 128 + (pe ? 8 : 12);

        bf16x8 A[2][4];
        #pragma unroll
        for (int cc = 0; cc < 8; ++cc) {
            const float4 wa0 = *(const float4*)(wb0 + cc * 16);
            const float4 wa1 = *(const float4*)(wb1 + cc * 16);

            const float r0 = 1.f / (m0 * (wa0.y + wa0.w) + m1 * (wa1.y + wa1.w)); // po=0
            const float r1 = 1.f / (m0 * (wa0.x + wa0.z) + m1 * (wa1.x + wa1.z)); // po=1

            A[0][0][cc] = (short)f2bf(m0 * wa0.y * r0);
            A[0][1][cc] = (short)f2bf(m0 * wa0.w * r0);
            A[0][2][cc] = (short)f2bf(m1 * wa1.y * r0);
            A[0][3][cc] = (short)f2bf(m1 * wa1.w * r0);
            A[1][0][cc] = (short)f2bf(m0 * wa0.x * r1);
            A[1][1][cc] = (short)f2bf(m0 * wa0.z * r1);
            A[1][2][cc] = (short)f2bf(m1 * wa1.x * r1);
            A[1][3][cc] = (short)f2bf(m1 * wa1.z * r1);
        }

        const int lr0 = pe ? 2 : 1;
        const int lr1 = pe ? 1 : 0;
        const int ho  = 2 * row + pe;

        #pragma unroll
        for (int nt = 0; nt < 3; ++nt) {
            const int col = c0 + nt * 16 + n16;
            const int lp  = col + 1;

            const bf16x8 B00 = *(const bf16x8*)(&xs[lr0][lp][g * 8]);
            const bf16x8 B0m = *(const bf16x8*)(&xs[lr0][lp - 1][g * 8]);
            const bf16x8 B0p = *(const bf16x8*)(&xs[lr0][lp + 1][g * 8]);
            const bf16x8 B10 = *(const bf16x8*)(&xs[lr1][lp][g * 8]);
            const bf16x8 B1m = *(const bf16x8*)(&xs[lr1][lp - 1][g * 8]);
            const bf16x8 B1p = *(const bf16x8*)(&xs[lr1][lp + 1][g * 8]);

            __builtin_amdgcn_s_setprio(1);
            f32x4 a0 = {0.f, 0.f, 0.f, 0.f}, a1 = {0.f, 0.f, 0.f, 0.f};
            a0 = __builtin_amdgcn_mfma_f32_16x16x32_bf16(A[0][0], B00, a0, 0, 0, 0);
            a0 = __builtin_amdgcn_mfma_f32_16x16x32_bf16(A[0][1], B0m, a0, 0, 0, 0);
            a0 = __builtin_amdgcn_mfma_f32_16x16x32_bf16(A[0][2], B10, a0, 0, 0, 0);
            a0 = __builtin_amdgcn_mfma_f32_16x16x32_bf16(A[0][3], B1m, a0, 0, 0, 0);
            a1 = __builtin_amdgcn_mfma_f32_16x16x32_bf16(A[1][0], B0p, a1, 0, 0, 0);
            a1 = __builtin_amdgcn_mfma_f32_16x16x32_bf16(A[1][1], B00, a1, 0, 0, 0);
            a1 = __builtin_amdgcn_mfma_f32_16x16x32_bf16(A[1][2], B1p, a1, 0, 0, 0);
            a1 = __builtin_amdgcn_mfma_f32_16x16x32_bf16(A[1][3], B10, a1, 0, 0, 0);
            __builtin_amdgcn_s_setprio(0);

            #pragma unroll
            for (int r = 0; r < 4; ++r) {
                const int oo = mt * 16 + 4 * g + r;
                const float v0 = a0[r] + bv4[r];
                const float v1 = a1[r] + bv4[r];
                float* p = out + ((size_t)(b * O_OUT + oo) * H_OUT + ho) * W_OUT + 2 * col;
                if (col == 0)             p[1] = v1;          // wo=0 is col-frame
                else if (col == W_IN - 1) p[0] = v0;          // wo=191 is col-frame
                else                      *(float2*)p = make_float2(v0, v1);
            }
        }
    } else {
        // ---- frame: border columns wo in {0,191}, ho 0..191 (corners incl.) ----
        float* xcol = (float*)smem;              // [32][96]

        const int fb   = blk - NCBLK;            // 0..15
        const int b    = fb >> 3;
        const int side = (fb >> 2) & 1;
        const int og   = fb & 3;
        const int colx = side ? 95 : 0;

        for (int idx = tid; idx < C_IN * H_IN; idx += 768) {
            const int c = idx / H_IN;
            const int r = idx - c * H_IN;
            xcol[c * H_IN + r] = x[(size_t)(b * C_IN + c) * HW_IN + r * W_IN + colx];
        }
        __syncthreads();

        if (tid < 384) {
            const int o_loc  = tid >> 5;
            const int ho_loc = tid & 31;
            const int o      = og * 12 + o_loc;
            const int wo     = side ? 191 : 0;
            const int pe     = ho_loc & 1;
            const int jstar  = side ? 2 : 1;

            int   rA[6], rB[6];
            float mBf[6];
            #pragma unroll
            for (int k = 0; k < 6; ++k) {
                const int ho = ho_loc + 32 * k;
                const int s  = ho >> 1;
                rA[k] = s;
                if (pe) { const bool m = (s + 1 < H_IN); rB[k] = m ? s + 1 : H_IN - 1; mBf[k] = m ? 1.f : 0.f; }
                else    { const bool m = (s > 0);        rB[k] = m ? s - 1 : 0;        mBf[k] = m ? 1.f : 0.f; }
            }

            const int iA = pe ? 8 : 4;
            const int iB = pe ? 0 : 12;

            float acc[6] = {0.f, 0.f, 0.f, 0.f, 0.f, 0.f};
            const float* wb = weight + (size_t)o * (C_IN * 16);

            for (int c = 0; c < C_IN; ++c) {
                const float wA = wb[c * 16 + iA + jstar];
                const float wB = wb[c * 16 + iB + jstar];
                const float rn_int  = __builtin_amdgcn_rcpf(wA + wB);
                const float rn_edge = __builtin_amdgcn_rcpf(wA);
                const float* xc = xcol + c * H_IN;
                #pragma unroll
                for (int k = 0; k < 6; ++k) {
                    const float xA = xc[rA[k]];
                    const float xB = xc[rB[k]];
                    const float rn = (mBf[k] != 0.f) ? rn_int : rn_edge;
                    acc[k] += (wA * xA + mBf[k] * (wB * xB)) * rn;
                }
            }

            const float bv = bias[o];
            #pragma unroll
            for (int k = 0; k < 6; ++k) {
                const int ho = ho_loc + 32 * k;
                out[((size_t)(b * O_OUT + o) * H_OUT + ho) * W_OUT + wo] = acc[k] + bv;
            }
        }
    }
}

extern "C" void kernel_launch(void* const* d_in, const int* in_sizes, int n_in,
                              void* d_out, int out_size, void* d_ws, size_t ws_size,
                              hipStream_t stream) {
    const float* x    = (const float*)d_in[0];
    const float* w    = (const float*)d_in[1];
    const float* bias = (const float*)d_in[2];
    float* out = (float*)d_out;

    dim3 b768(768, 1, 1);
    dim3 gm(NCBLK + NFBLK, 1, 1);                  // 208 blocks, single launch
    hipLaunchKernelGGL(nct_all, gm, b768, 0, stream, x, w, bias, out);
}